// Round 2
// baseline (64867.633 us; speedup 1.0000x reference)
//
#include <hip/hip_runtime.h>
#include <math.h>

#define D 256
#define SEQ 1000
#define NB 32
#define PATCH 160
#define NL 6
#define M_TOTAL (NB * SEQ)   // 32000
#define G3 (3 * D)           // 768

typedef __attribute__((ext_vector_type(2))) _Float16 half2_t;
typedef __attribute__((ext_vector_type(4))) _Float16 half4_t;
typedef __attribute__((ext_vector_type(8))) _Float16 half8_t;

__device__ __forceinline__ float gelu_exact(float v) {
    return 0.5f * v * (1.0f + erff(v * 0.70710678118654752440f));
}

#if defined(__has_builtin) && __has_builtin(__builtin_amdgcn_fdot2)
__device__ __forceinline__ float fdot2_(half2_t a, half2_t b, float c) {
    return __builtin_amdgcn_fdot2(a, b, c, false);
}
#else
__device__ __forceinline__ float fdot2_(half2_t a, half2_t b, float c) {
    return fmaf((float)a.x, (float)b.x, fmaf((float)a.y, (float)b.y, c));
}
#endif

// ---------------------------------------------------------------------------
// Kernel 1: conv patchify GEMM + exact GELU + pos_emb add
// ---------------------------------------------------------------------------
__global__ __launch_bounds__(256) void conv_gelu_pos(
    const float* __restrict__ wav, const float* __restrict__ cw,
    const float* __restrict__ pos, float* __restrict__ x)
{
    __shared__ float As[64][33];
    __shared__ float Bs[32][65];
    const int m0 = blockIdx.x * 64;
    const int n0 = blockIdx.y * 64;
    const int tid = threadIdx.x;
    const int tx = tid & 15;      // 0..15 -> n
    const int ty = tid >> 4;      // 0..15 -> m
    float acc[4][4] = {};

    for (int kc = 0; kc < PATCH; kc += 32) {
        for (int p = 0; p < 8; ++p) {
            int mr = p * 8 + (tid >> 5);
            int kk = tid & 31;
            int m = m0 + mr;
            int b = m / SEQ, s = m % SEQ;
            As[mr][kk] = wav[(size_t)b * 160000 + (size_t)s * PATCH + kc + kk];
        }
        for (int p = 0; p < 8; ++p) {
            int kr = p * 4 + (tid >> 6);
            int nn = tid & 63;
            Bs[kr][nn] = cw[(size_t)(kc + kr) * D + n0 + nn];
        }
        __syncthreads();
        #pragma unroll
        for (int kk = 0; kk < 32; ++kk) {
            float a[4], bb[4];
            #pragma unroll
            for (int i = 0; i < 4; ++i) a[i] = As[ty * 4 + i][kk];
            #pragma unroll
            for (int j = 0; j < 4; ++j) bb[j] = Bs[kk][tx * 4 + j];
            #pragma unroll
            for (int i = 0; i < 4; ++i)
                #pragma unroll
                for (int j = 0; j < 4; ++j)
                    acc[i][j] = fmaf(a[i], bb[j], acc[i][j]);
        }
        __syncthreads();
    }
    #pragma unroll
    for (int i = 0; i < 4; ++i) {
        int m = m0 + ty * 4 + i;
        int s = m % SEQ;
        int n = n0 + tx * 4;
        float4 v;
        v.x = gelu_exact(acc[i][0]) + pos[(size_t)s * D + n + 0];
        v.y = gelu_exact(acc[i][1]) + pos[(size_t)s * D + n + 1];
        v.z = gelu_exact(acc[i][2]) + pos[(size_t)s * D + n + 2];
        v.w = gelu_exact(acc[i][3]) + pos[(size_t)s * D + n + 3];
        *(float4*)&x[(size_t)m * D + n] = v;
    }
}

// ---------------------------------------------------------------------------
// Kernel 2: per-row mean / rstd
// ---------------------------------------------------------------------------
__global__ __launch_bounds__(64) void row_stats(
    const float* __restrict__ x, float* __restrict__ st)
{
    const int m = blockIdx.x;
    const int t = threadIdx.x;
    const float* r = x + (size_t)m * D;
    float s = 0.f, q = 0.f;
    #pragma unroll
    for (int i = 0; i < 4; ++i) {
        float v = r[t + 64 * i];
        s += v;
        q += v * v;
    }
    #pragma unroll
    for (int o = 32; o > 0; o >>= 1) {
        s += __shfl_down(s, o);
        q += __shfl_down(q, o);
    }
    if (t == 0) {
        float mu = s * (1.f / 256.f);
        float var = q * (1.f / 256.f) - mu * mu;
        st[2 * m]     = mu;
        st[2 * m + 1] = rsqrtf(var + 1e-5f);
    }
}

// ---------------------------------------------------------------------------
// Kernel 3: fused LN + input-projection GEMM
// ---------------------------------------------------------------------------
__global__ __launch_bounds__(256) void ln_xp_gemm(
    const float* __restrict__ x, const float* __restrict__ st,
    const float* __restrict__ lnsc, const float* __restrict__ lnbi,
    const float* __restrict__ wih, const float* __restrict__ bih,
    float* __restrict__ xp)
{
    __shared__ float As[64][33];
    __shared__ float Bs[32][65];
    __shared__ float sc[D], bi[D];
    const int m0 = blockIdx.x * 64;
    const int n0 = blockIdx.y * 64;
    const int tid = threadIdx.x;
    const int tx = tid & 15;
    const int ty = tid >> 4;
    sc[tid] = lnsc[tid];
    bi[tid] = lnbi[tid];
    float acc[4][4] = {};

    for (int kc = 0; kc < D; kc += 32) {
        for (int p = 0; p < 8; ++p) {
            int mr = p * 8 + (tid >> 5);
            int kk = tid & 31;
            int m = m0 + mr;
            float mu = st[2 * m], rs = st[2 * m + 1];
            float v = x[(size_t)m * D + kc + kk];
            As[mr][kk] = (v - mu) * rs * sc[kc + kk] + bi[kc + kk];
        }
        for (int p = 0; p < 8; ++p) {
            int nr = p * 8 + (tid >> 5);
            int kk = tid & 31;
            Bs[kk][nr] = wih[(size_t)(n0 + nr) * D + kc + kk];
        }
        __syncthreads();
        #pragma unroll
        for (int kk = 0; kk < 32; ++kk) {
            float a[4], bb[4];
            #pragma unroll
            for (int i = 0; i < 4; ++i) a[i] = As[ty * 4 + i][kk];
            #pragma unroll
            for (int j = 0; j < 4; ++j) bb[j] = Bs[kk][tx * 4 + j];
            #pragma unroll
            for (int i = 0; i < 4; ++i)
                #pragma unroll
                for (int j = 0; j < 4; ++j)
                    acc[i][j] = fmaf(a[i], bb[j], acc[i][j]);
        }
        __syncthreads();
    }
    #pragma unroll
    for (int i = 0; i < 4; ++i) {
        int m = m0 + ty * 4 + i;
        int n = n0 + tx * 4;
        float4 v;
        v.x = acc[i][0] + bih[n + 0];
        v.y = acc[i][1] + bih[n + 1];
        v.z = acc[i][2] + bih[n + 2];
        v.w = acc[i][3] + bih[n + 3];
        *(float4*)&xp[(size_t)m * G3 + n] = v;
    }
}

// ---------------------------------------------------------------------------
// Kernel 4: persistent-register GRU recurrence.
// One block per batch (32 blocks), 768 threads = 12 waves (3/SIMD).
// Thread g holds w_hh row g as 128 half2 VGPRs (fp16). h in LDS (fp16 for
// dot, fp32 for blend). Per step: 128 v_dot2_f32_f16 per thread, gates via
// LDS, 256 threads do the nonlinearity + residual write.
// ---------------------------------------------------------------------------
__global__ __launch_bounds__(768, 3) void gru_scan_persist(
    const float* __restrict__ xp, const float* __restrict__ whh,
    const float* __restrict__ bhh, float* __restrict__ x)
{
    __shared__ float gates[G3];
    __shared__ float xn_s[D];
    __shared__ float hf[D];
    __shared__ __align__(16) _Float16 h16[D];

    const int g = threadIdx.x;   // 0..767 gate-row
    const int b = blockIdx.x;

    // ---- preload weights: row g of whh -> 128 half2 regs ----
    half2_t w[128];
    {
        const float4* wrow = (const float4*)(whh + (size_t)g * D);
        #pragma unroll
        for (int i = 0; i < 64; ++i) {
            float4 v = wrow[i];
            half2_t lo = {(_Float16)v.x, (_Float16)v.y};
            half2_t hi = {(_Float16)v.z, (_Float16)v.w};
            w[2 * i + 0] = lo;
            w[2 * i + 1] = hi;
        }
    }
    const float bh = bhh[g];

    if (g < D) {
        hf[g] = 0.f;
        h16[g] = (_Float16)0.f;
    }
    const float* xpb = xp + (size_t)b * SEQ * G3;
    float* xb = x + (size_t)b * SEQ * D;
    __syncthreads();

    for (int t = 0; t < SEQ; ++t) {
        // prefetch (independent of h)
        float xpv = xpb[(size_t)t * G3 + g];
        float xold = 0.f;
        if (g < D) xold = xb[(size_t)t * D + g];

        float acc0 = 0.f, acc1 = 0.f;
        const half8_t* hp = (const half8_t*)h16;
        #pragma unroll
        for (int i = 0; i < 32; ++i) {
            half8_t hv = hp[i];   // broadcast ds_read_b128, k = 8i..8i+7
            acc0 = fdot2_(w[4 * i + 0], hv.lo.lo, acc0);
            acc1 = fdot2_(w[4 * i + 1], hv.lo.hi, acc1);
            acc0 = fdot2_(w[4 * i + 2], hv.hi.lo, acc0);
            acc1 = fdot2_(w[4 * i + 3], hv.hi.hi, acc1);
        }
        float gv = acc0 + acc1 + bh;
        if (g < 2 * D) gv += xpv;          // fold x-part into r,z rows
        else xn_s[g - 2 * D] = xpv;        // n-row x-part kept separate
        gates[g] = gv;
        __syncthreads();

        if (g < D) {
            const int d = g;
            float r = 1.f / (1.f + expf(-gates[d]));
            float z = 1.f / (1.f + expf(-gates[D + d]));
            float n = tanhf(xn_s[d] + r * gates[2 * D + d]);
            float hold = hf[d];
            float hnew = (1.f - z) * n + z * hold;
            xb[(size_t)t * D + d] = xold + hnew;
            hf[d] = hnew;
            h16[d] = (_Float16)hnew;
        }
        __syncthreads();
    }
}

// ---------------------------------------------------------------------------
// Kernel 5: final LN + mean-pool over sequence
// ---------------------------------------------------------------------------
__global__ __launch_bounds__(256) void pool_ln(
    const float* __restrict__ x, const float* __restrict__ st,
    const float* __restrict__ fsc, const float* __restrict__ fbi,
    float* __restrict__ emb)
{
    const int b = blockIdx.x;
    const int d = threadIdx.x;
    float acc = 0.f;
    for (int s = 0; s < SEQ; ++s) {
        int m = b * SEQ + s;
        acc += (x[(size_t)m * D + d] - st[2 * m]) * st[2 * m + 1];
    }
    emb[b * D + d] = (acc * (1.f / (float)SEQ)) * fsc[d] + fbi[d];
}

// ---------------------------------------------------------------------------
// Kernel 6: classification head (tiny). Single block.
// ---------------------------------------------------------------------------
__global__ __launch_bounds__(256) void head_mlp(
    const float* __restrict__ emb, const float* __restrict__ w1,
    const float* __restrict__ b1, const float* __restrict__ w2,
    const float* __restrict__ b2, float* __restrict__ out)
{
    __shared__ float es[NB][D + 1];
    __shared__ float h1[NB][128 + 1];
    const int t = threadIdx.x;
    for (int i = t; i < NB * D; i += 256) es[i / D][i % D] = emb[i];
    __syncthreads();
    for (int i = t; i < NB * 128; i += 256) {
        int bb = i / 128, j = i % 128;
        float a = b1[j];
        for (int k = 0; k < D; ++k) a = fmaf(es[bb][k], w1[(size_t)k * 128 + j], a);
        h1[bb][j] = gelu_exact(a);
    }
    __syncthreads();
    for (int i = t; i < NB * 8; i += 256) {
        int bb = i / 8, c = i % 8;
        float a = b2[c];
        for (int k = 0; k < 128; ++k) a = fmaf(h1[bb][k], w2[(size_t)k * 8 + c], a);
        out[i] = a;
    }
}

// ---------------------------------------------------------------------------
extern "C" void kernel_launch(void* const* d_in, const int* in_sizes, int n_in,
                              void* d_out, int out_size, void* d_ws, size_t ws_size,
                              hipStream_t stream)
{
    const float* wav  = (const float*)d_in[0];
    const float* cw   = (const float*)d_in[1];
    const float* pos  = (const float*)d_in[2];
    const float* lnsc = (const float*)d_in[3];
    const float* lnbi = (const float*)d_in[4];
    const float* wih  = (const float*)d_in[5];
    const float* whh  = (const float*)d_in[6];
    const float* bih  = (const float*)d_in[7];
    const float* bhh  = (const float*)d_in[8];
    const float* fsc  = (const float*)d_in[9];
    const float* fbi  = (const float*)d_in[10];
    const float* hw1  = (const float*)d_in[11];
    const float* hb1  = (const float*)d_in[12];
    const float* hw2  = (const float*)d_in[13];
    const float* hb2  = (const float*)d_in[14];

    float* ws    = (float*)d_ws;
    float* x     = ws;                        // 8,192,000 f
    float* xp    = x + (size_t)M_TOTAL * D;   // 24,576,000 f
    float* st    = xp + (size_t)M_TOTAL * G3; // 64,000 f
    float* emb   = st + 2 * M_TOTAL;          // 8,192 f

    conv_gelu_pos<<<dim3(M_TOTAL / 64, D / 64), 256, 0, stream>>>(wav, cw, pos, x);

    for (int l = 0; l < NL; ++l) {
        row_stats<<<M_TOTAL, 64, 0, stream>>>(x, st);
        ln_xp_gemm<<<dim3(M_TOTAL / 64, G3 / 64), 256, 0, stream>>>(
            x, st, lnsc + (size_t)l * D, lnbi + (size_t)l * D,
            wih + (size_t)l * G3 * D, bih + (size_t)l * G3, xp);
        gru_scan_persist<<<NB, 768, 0, stream>>>(
            xp, whh + (size_t)l * G3 * D, bhh + (size_t)l * G3, x);
    }

    row_stats<<<M_TOTAL, 64, 0, stream>>>(x, st);
    pool_ln<<<NB, D, 0, stream>>>(x, st, fsc, fbi, emb);
    head_mlp<<<1, 256, 0, stream>>>(emb, hw1, hb1, hw2, hb2, (float*)d_out);
}

// Round 3
// 61471.429 us; speedup vs baseline: 1.0552x; 1.0552x over previous
//
#include <hip/hip_runtime.h>
#include <math.h>

#define D 256
#define SEQ 1000
#define NB 32
#define PATCH 160
#define NL 6
#define M_TOTAL (NB * SEQ)   // 32000
#define G3 (3 * D)           // 768

typedef __attribute__((ext_vector_type(2))) _Float16 half2_t;
typedef __attribute__((ext_vector_type(8))) _Float16 half8_t;
typedef __attribute__((ext_vector_type(64))) _Float16 half64_t;

__device__ __forceinline__ float gelu_exact(float v) {
    return 0.5f * v * (1.0f + erff(v * 0.70710678118654752440f));
}

#if defined(__has_builtin) && __has_builtin(__builtin_amdgcn_fdot2)
__device__ __forceinline__ float fdot2_(half2_t a, half2_t b, float c) {
    return __builtin_amdgcn_fdot2(a, b, c, false);
}
#else
__device__ __forceinline__ float fdot2_(half2_t a, half2_t b, float c) {
    return fmaf((float)a.x, (float)b.x, fmaf((float)a.y, (float)b.y, c));
}
#endif

// extract half2 #i (elements 2i,2i+1 — one VGPR) from a 64-wide fp16 vector
__device__ __forceinline__ half2_t h2at(half64_t v, int i) {
    half2_t r; r.x = v[2 * i]; r.y = v[2 * i + 1]; return r;
}
__device__ __forceinline__ half2_t h2of8(half8_t v, int i) {
    half2_t r; r.x = v[2 * i]; r.y = v[2 * i + 1]; return r;
}

// ---------------------------------------------------------------------------
// Kernel 0: fp32 -> fp16 weight conversion (all 6 layers of w_hh, once)
// ---------------------------------------------------------------------------
__global__ __launch_bounds__(256) void cvt_whh_fp16(
    const float* __restrict__ src, _Float16* __restrict__ dst)
{
    int i = blockIdx.x * 256 + threadIdx.x;   // grid sized exactly
    float4 v = ((const float4*)src)[i];
    half8_t o;
    o[0] = (_Float16)v.x; o[1] = (_Float16)v.y;
    o[2] = (_Float16)v.z; o[3] = (_Float16)v.w;
    // write 4 halves (8 bytes)
    ((ushort1*)0); // no-op
    _Float16* d = dst + 4 * (size_t)i;
    d[0] = o[0]; d[1] = o[1]; d[2] = o[2]; d[3] = o[3];
}

// ---------------------------------------------------------------------------
// Kernel 1: conv patchify GEMM + exact GELU + pos_emb add
// ---------------------------------------------------------------------------
__global__ __launch_bounds__(256) void conv_gelu_pos(
    const float* __restrict__ wav, const float* __restrict__ cw,
    const float* __restrict__ pos, float* __restrict__ x)
{
    __shared__ float As[64][33];
    __shared__ float Bs[32][65];
    const int m0 = blockIdx.x * 64;
    const int n0 = blockIdx.y * 64;
    const int tid = threadIdx.x;
    const int tx = tid & 15;      // 0..15 -> n
    const int ty = tid >> 4;      // 0..15 -> m
    float acc[4][4] = {};

    for (int kc = 0; kc < PATCH; kc += 32) {
        for (int p = 0; p < 8; ++p) {
            int mr = p * 8 + (tid >> 5);
            int kk = tid & 31;
            int m = m0 + mr;
            int b = m / SEQ, s = m % SEQ;
            As[mr][kk] = wav[(size_t)b * 160000 + (size_t)s * PATCH + kc + kk];
        }
        for (int p = 0; p < 8; ++p) {
            int kr = p * 4 + (tid >> 6);
            int nn = tid & 63;
            Bs[kr][nn] = cw[(size_t)(kc + kr) * D + n0 + nn];
        }
        __syncthreads();
        #pragma unroll
        for (int kk = 0; kk < 32; ++kk) {
            float a[4], bb[4];
            #pragma unroll
            for (int i = 0; i < 4; ++i) a[i] = As[ty * 4 + i][kk];
            #pragma unroll
            for (int j = 0; j < 4; ++j) bb[j] = Bs[kk][tx * 4 + j];
            #pragma unroll
            for (int i = 0; i < 4; ++i)
                #pragma unroll
                for (int j = 0; j < 4; ++j)
                    acc[i][j] = fmaf(a[i], bb[j], acc[i][j]);
        }
        __syncthreads();
    }
    #pragma unroll
    for (int i = 0; i < 4; ++i) {
        int m = m0 + ty * 4 + i;
        int s = m % SEQ;
        int n = n0 + tx * 4;
        float4 v;
        v.x = gelu_exact(acc[i][0]) + pos[(size_t)s * D + n + 0];
        v.y = gelu_exact(acc[i][1]) + pos[(size_t)s * D + n + 1];
        v.z = gelu_exact(acc[i][2]) + pos[(size_t)s * D + n + 2];
        v.w = gelu_exact(acc[i][3]) + pos[(size_t)s * D + n + 3];
        *(float4*)&x[(size_t)m * D + n] = v;
    }
}

// ---------------------------------------------------------------------------
// Kernel 2: per-row mean / rstd
// ---------------------------------------------------------------------------
__global__ __launch_bounds__(64) void row_stats(
    const float* __restrict__ x, float* __restrict__ st)
{
    const int m = blockIdx.x;
    const int t = threadIdx.x;
    const float* r = x + (size_t)m * D;
    float s = 0.f, q = 0.f;
    #pragma unroll
    for (int i = 0; i < 4; ++i) {
        float v = r[t + 64 * i];
        s += v;
        q += v * v;
    }
    #pragma unroll
    for (int o = 32; o > 0; o >>= 1) {
        s += __shfl_down(s, o);
        q += __shfl_down(q, o);
    }
    if (t == 0) {
        float mu = s * (1.f / 256.f);
        float var = q * (1.f / 256.f) - mu * mu;
        st[2 * m]     = mu;
        st[2 * m + 1] = rsqrtf(var + 1e-5f);
    }
}

// ---------------------------------------------------------------------------
// Kernel 3: fused LN + input-projection GEMM
// ---------------------------------------------------------------------------
__global__ __launch_bounds__(256) void ln_xp_gemm(
    const float* __restrict__ x, const float* __restrict__ st,
    const float* __restrict__ lnsc, const float* __restrict__ lnbi,
    const float* __restrict__ wih, const float* __restrict__ bih,
    float* __restrict__ xp)
{
    __shared__ float As[64][33];
    __shared__ float Bs[32][65];
    __shared__ float sc[D], bi[D];
    const int m0 = blockIdx.x * 64;
    const int n0 = blockIdx.y * 64;
    const int tid = threadIdx.x;
    const int tx = tid & 15;
    const int ty = tid >> 4;
    sc[tid] = lnsc[tid];
    bi[tid] = lnbi[tid];
    float acc[4][4] = {};

    for (int kc = 0; kc < D; kc += 32) {
        for (int p = 0; p < 8; ++p) {
            int mr = p * 8 + (tid >> 5);
            int kk = tid & 31;
            int m = m0 + mr;
            float mu = st[2 * m], rs = st[2 * m + 1];
            float v = x[(size_t)m * D + kc + kk];
            As[mr][kk] = (v - mu) * rs * sc[kc + kk] + bi[kc + kk];
        }
        for (int p = 0; p < 8; ++p) {
            int nr = p * 8 + (tid >> 5);
            int kk = tid & 31;
            Bs[kk][nr] = wih[(size_t)(n0 + nr) * D + kc + kk];
        }
        __syncthreads();
        #pragma unroll
        for (int kk = 0; kk < 32; ++kk) {
            float a[4], bb[4];
            #pragma unroll
            for (int i = 0; i < 4; ++i) a[i] = As[ty * 4 + i][kk];
            #pragma unroll
            for (int j = 0; j < 4; ++j) bb[j] = Bs[kk][tx * 4 + j];
            #pragma unroll
            for (int i = 0; i < 4; ++i)
                #pragma unroll
                for (int j = 0; j < 4; ++j)
                    acc[i][j] = fmaf(a[i], bb[j], acc[i][j]);
        }
        __syncthreads();
    }
    #pragma unroll
    for (int i = 0; i < 4; ++i) {
        int m = m0 + ty * 4 + i;
        int n = n0 + tx * 4;
        float4 v;
        v.x = acc[i][0] + bih[n + 0];
        v.y = acc[i][1] + bih[n + 1];
        v.z = acc[i][2] + bih[n + 2];
        v.w = acc[i][3] + bih[n + 3];
        *(float4*)&xp[(size_t)m * G3 + n] = v;
    }
}

// ---------------------------------------------------------------------------
// Kernel 4: persistent-register GRU recurrence.
// One block per batch (32 blocks), 768 threads = 12 waves (3/SIMD, VGPR<=170).
// Thread g holds w_hh row g as FOUR half64_t SSA values (4 x 32 = 128 VGPRs,
// cannot be scratch-demoted). h in LDS (fp16 for dot, fp32 for blend).
// Per step: 128 v_dot2_f32_f16 per thread, gates via LDS, 256 threads do the
// nonlinearity + residual write.
// ---------------------------------------------------------------------------
__global__ __launch_bounds__(768) void gru_scan_persist(
    const float* __restrict__ xp, const _Float16* __restrict__ whh16,
    const float* __restrict__ bhh, float* __restrict__ x)
{
    __shared__ float gates[G3];
    __shared__ float xn_s[D];
    __shared__ float hf[D];
    __shared__ __align__(16) _Float16 h16[D];

    const int g = threadIdx.x;   // 0..767 gate-row
    const int b = blockIdx.x;

    // ---- preload weights: row g as 4 x half64_t (direct fp16 loads) ----
    const half64_t* wp = (const half64_t*)(whh16 + (size_t)g * D);
    half64_t w0 = wp[0];
    half64_t w1 = wp[1];
    half64_t w2 = wp[2];
    half64_t w3 = wp[3];
    const float bh = bhh[g];

    if (g < D) {
        hf[g] = 0.f;
        h16[g] = (_Float16)0.f;
    }
    const float* xpb = xp + (size_t)b * SEQ * G3;
    float* xb = x + (size_t)b * SEQ * D;
    __syncthreads();

    for (int t = 0; t < SEQ; ++t) {
        // prefetch (independent of h)
        float xpv = xpb[(size_t)t * G3 + g];
        float xold = 0.f;
        if (g < D) xold = xb[(size_t)t * D + g];

        float acc0 = 0.f, acc1 = 0.f;
        const half8_t* hp = (const half8_t*)h16;
        #pragma unroll
        for (int i = 0; i < 8; ++i) {       // k = 64*0 .. : quarter 0
            half8_t hv = hp[i];
            acc0 = fdot2_(h2at(w0, 4 * i + 0), h2of8(hv, 0), acc0);
            acc1 = fdot2_(h2at(w0, 4 * i + 1), h2of8(hv, 1), acc1);
            acc0 = fdot2_(h2at(w0, 4 * i + 2), h2of8(hv, 2), acc0);
            acc1 = fdot2_(h2at(w0, 4 * i + 3), h2of8(hv, 3), acc1);
        }
        #pragma unroll
        for (int i = 0; i < 8; ++i) {       // quarter 1
            half8_t hv = hp[8 + i];
            acc0 = fdot2_(h2at(w1, 4 * i + 0), h2of8(hv, 0), acc0);
            acc1 = fdot2_(h2at(w1, 4 * i + 1), h2of8(hv, 1), acc1);
            acc0 = fdot2_(h2at(w1, 4 * i + 2), h2of8(hv, 2), acc0);
            acc1 = fdot2_(h2at(w1, 4 * i + 3), h2of8(hv, 3), acc1);
        }
        #pragma unroll
        for (int i = 0; i < 8; ++i) {       // quarter 2
            half8_t hv = hp[16 + i];
            acc0 = fdot2_(h2at(w2, 4 * i + 0), h2of8(hv, 0), acc0);
            acc1 = fdot2_(h2at(w2, 4 * i + 1), h2of8(hv, 1), acc1);
            acc0 = fdot2_(h2at(w2, 4 * i + 2), h2of8(hv, 2), acc0);
            acc1 = fdot2_(h2at(w2, 4 * i + 3), h2of8(hv, 3), acc1);
        }
        #pragma unroll
        for (int i = 0; i < 8; ++i) {       // quarter 3
            half8_t hv = hp[24 + i];
            acc0 = fdot2_(h2at(w3, 4 * i + 0), h2of8(hv, 0), acc0);
            acc1 = fdot2_(h2at(w3, 4 * i + 1), h2of8(hv, 1), acc1);
            acc0 = fdot2_(h2at(w3, 4 * i + 2), h2of8(hv, 2), acc0);
            acc1 = fdot2_(h2at(w3, 4 * i + 3), h2of8(hv, 3), acc1);
        }

        float gv = acc0 + acc1 + bh;
        if (g < 2 * D) gv += xpv;          // fold x-part into r,z rows
        else xn_s[g - 2 * D] = xpv;        // n-row x-part kept separate
        gates[g] = gv;
        __syncthreads();

        if (g < D) {
            const int d = g;
            float r = 1.f / (1.f + expf(-gates[d]));
            float z = 1.f / (1.f + expf(-gates[D + d]));
            float n = tanhf(xn_s[d] + r * gates[2 * D + d]);
            float hold = hf[d];
            float hnew = (1.f - z) * n + z * hold;
            xb[(size_t)t * D + d] = xold + hnew;
            hf[d] = hnew;
            h16[d] = (_Float16)hnew;
        }
        __syncthreads();
    }
}

// ---------------------------------------------------------------------------
// Kernel 5: final LN + mean-pool over sequence
// ---------------------------------------------------------------------------
__global__ __launch_bounds__(256) void pool_ln(
    const float* __restrict__ x, const float* __restrict__ st,
    const float* __restrict__ fsc, const float* __restrict__ fbi,
    float* __restrict__ emb)
{
    const int b = blockIdx.x;
    const int d = threadIdx.x;
    float acc = 0.f;
    for (int s = 0; s < SEQ; ++s) {
        int m = b * SEQ + s;
        acc += (x[(size_t)m * D + d] - st[2 * m]) * st[2 * m + 1];
    }
    emb[b * D + d] = (acc * (1.f / (float)SEQ)) * fsc[d] + fbi[d];
}

// ---------------------------------------------------------------------------
// Kernel 6: classification head (tiny). Single block.
// ---------------------------------------------------------------------------
__global__ __launch_bounds__(256) void head_mlp(
    const float* __restrict__ emb, const float* __restrict__ w1,
    const float* __restrict__ b1, const float* __restrict__ w2,
    const float* __restrict__ b2, float* __restrict__ out)
{
    __shared__ float es[NB][D + 1];
    __shared__ float h1[NB][128 + 1];
    const int t = threadIdx.x;
    for (int i = t; i < NB * D; i += 256) es[i / D][i % D] = emb[i];
    __syncthreads();
    for (int i = t; i < NB * 128; i += 256) {
        int bb = i / 128, j = i % 128;
        float a = b1[j];
        for (int k = 0; k < D; ++k) a = fmaf(es[bb][k], w1[(size_t)k * 128 + j], a);
        h1[bb][j] = gelu_exact(a);
    }
    __syncthreads();
    for (int i = t; i < NB * 8; i += 256) {
        int bb = i / 8, c = i % 8;
        float a = b2[c];
        for (int k = 0; k < 128; ++k) a = fmaf(h1[bb][k], w2[(size_t)k * 8 + c], a);
        out[i] = a;
    }
}

// ---------------------------------------------------------------------------
extern "C" void kernel_launch(void* const* d_in, const int* in_sizes, int n_in,
                              void* d_out, int out_size, void* d_ws, size_t ws_size,
                              hipStream_t stream)
{
    const float* wav  = (const float*)d_in[0];
    const float* cw   = (const float*)d_in[1];
    const float* pos  = (const float*)d_in[2];
    const float* lnsc = (const float*)d_in[3];
    const float* lnbi = (const float*)d_in[4];
    const float* wih  = (const float*)d_in[5];
    const float* whh  = (const float*)d_in[6];
    const float* bih  = (const float*)d_in[7];
    const float* bhh  = (const float*)d_in[8];
    const float* fsc  = (const float*)d_in[9];
    const float* fbi  = (const float*)d_in[10];
    const float* hw1  = (const float*)d_in[11];
    const float* hb1  = (const float*)d_in[12];
    const float* hw2  = (const float*)d_in[13];
    const float* hb2  = (const float*)d_in[14];

    float* ws    = (float*)d_ws;
    float* x     = ws;                        // 8,192,000 f
    float* xp    = x + (size_t)M_TOTAL * D;   // 24,576,000 f
    float* st    = xp + (size_t)M_TOTAL * G3; // 64,000 f
    float* emb   = st + 2 * M_TOTAL;          // 8,192 f
    _Float16* whh16 = (_Float16*)(emb + NB * D); // 6*768*256 halves = 2.36 MB

    // one-shot weight conversion (re-done every call; ~10 us)
    {
        const int total4 = NL * G3 * D / 4;   // float4 count = 294912
        cvt_whh_fp16<<<total4 / 256, 256, 0, stream>>>(whh, whh16);
    }

    conv_gelu_pos<<<dim3(M_TOTAL / 64, D / 64), 256, 0, stream>>>(wav, cw, pos, x);

    for (int l = 0; l < NL; ++l) {
        row_stats<<<M_TOTAL, 64, 0, stream>>>(x, st);
        ln_xp_gemm<<<dim3(M_TOTAL / 64, G3 / 64), 256, 0, stream>>>(
            x, st, lnsc + (size_t)l * D, lnbi + (size_t)l * D,
            wih + (size_t)l * G3 * D, bih + (size_t)l * G3, xp);
        gru_scan_persist<<<NB, 768, 0, stream>>>(
            xp, whh16 + (size_t)l * G3 * D, bhh + (size_t)l * G3, x);
    }

    row_stats<<<M_TOTAL, 64, 0, stream>>>(x, st);
    pool_ln<<<NB, D, 0, stream>>>(x, st, fsc, fbi, emb);
    head_mlp<<<1, 256, 0, stream>>>(emb, hw1, hb1, hw2, hb2, (float*)d_out);
}